// Round 18
// baseline (652.211 us; speedup 1.0000x reference)
//
#include <hip/hip_runtime.h>
#include <hip/hip_bf16.h>

// Decision Transformer forward, round 18.
// - m1 GEMM back to BM=128 (32 MFMA/wave/K-tile) now WITH dbuf (64KB LDS,
//   vmcnt(8)); other GEMMs stay BM=64 dbuf. Isolates tile-size x dbuf.
// B=8 T=512 S3=1536 E=512 H=8 D=64 L=3 FF=2048 MS=4096

#define S3 1536
#define EMB 512
#define NROWS 12288   // B*S3
#define NTOK 4096     // B*T
#define QKV_STR 1536
#define QSCALE 0.18033688f  // 0.125 * log2(e)
#define WT_L 3145728        // Wt elements per layer

typedef __hip_bfloat16 bf16;
typedef __attribute__((ext_vector_type(8))) short short8;   // 8 bf16
typedef __attribute__((ext_vector_type(4))) float f32x4;

__device__ inline float bf2f(bf16 b) { return __bfloat162float(b); }
__device__ inline bf16 f2bf(float f) { return __float2bfloat16(f); }
__device__ inline unsigned short f2bfu(float f) {
    bf16 h = __float2bfloat16(f);
    return *reinterpret_cast<unsigned short*>(&h);
}
__device__ inline float bfu2f(unsigned short v) {
    bf16 h = *reinterpret_cast<bf16*>(&v);
    return __bfloat162float(h);
}
__device__ inline float fast_gelu(float v) {
    float u = v * fmaf(v * v, 0.0356774081f, 0.7978845608f);
    return v * __builtin_amdgcn_rcpf(1.0f + exp2f(u * -2.885390082f));
}

__device__ inline void gload_lds16(const void* g, void* lds) {
    __builtin_amdgcn_global_load_lds(
        (const __attribute__((address_space(1))) void*)g,
        (__attribute__((address_space(3))) void*)lds, 16, 0, 0);
}

// ---------------- embed: writes bf16 residual stream ----------------
__global__ __launch_bounds__(256) void embed_v9(
    const float* __restrict__ state, const float* __restrict__ action,
    const float* __restrict__ reward, const int* __restrict__ timestep,
    const float* __restrict__ sW, const float* __restrict__ sb,
    const float* __restrict__ aW, const float* __restrict__ ab,
    const float* __restrict__ rW, const float* __restrict__ rb,
    const float* __restrict__ temb, bf16* __restrict__ hb)
{
    int tok = blockIdx.x;
    int b = tok >> 9;
    int t = tok & 511;
    int tid = threadIdx.x;
    int ts = timestep[tok];
    long hbase = ((long)b * S3 + 3L * t) * EMB;
    const float* st = state + (long)tok * 17;
    const float* ac = action + (long)tok * 6;
    float rw = reward[tok];
    float sv[17], av[6];
#pragma unroll
    for (int j = 0; j < 17; ++j) sv[j] = st[j];
#pragma unroll
    for (int j = 0; j < 6; ++j) av[j] = ac[j];
    for (int c = tid; c < EMB; c += 256) {
        float te = temb[(long)ts * EMB + c];
        float re = rw * rW[c] + rb[c] + te;
        float se = sb[c] + te;
#pragma unroll
        for (int j = 0; j < 17; ++j) se = fmaf(sv[j], sW[j * EMB + c], se);
        float ae = ab[c] + te;
#pragma unroll
        for (int j = 0; j < 6; ++j) ae = fmaf(av[j], aW[j * EMB + c], ae);
        hb[hbase + c] = f2bf(re);
        hb[hbase + EMB + c] = f2bf(se);
        hb[hbase + 2 * EMB + c] = f2bf(ae);
    }
}

// ------- (add+)layernorm, wave-per-row, shfl-only ---------
__global__ __launch_bounds__(256) void addln_v13(
    bf16* __restrict__ hb, const bf16* __restrict__ delta,
    const float* __restrict__ g, const float* __restrict__ bb, int hasDelta)
{
    int tid = threadIdx.x;
    int w = tid >> 6, l = tid & 63;
    long row = (long)blockIdx.x * 4 + w;
    long base = row * EMB + l * 8;
    short8 xv = *reinterpret_cast<const short8*>(&hb[base]);
    float x[8];
#pragma unroll
    for (int j = 0; j < 8; ++j) x[j] = bfu2f((unsigned short)xv[j]);
    if (hasDelta) {
        short8 dv = *reinterpret_cast<const short8*>(&delta[base]);
#pragma unroll
        for (int j = 0; j < 8; ++j) x[j] += bfu2f((unsigned short)dv[j]);
    }
    float s = 0.f;
#pragma unroll
    for (int j = 0; j < 8; ++j) s += x[j];
#pragma unroll
    for (int off = 32; off; off >>= 1) s += __shfl_xor(s, off);
    float mean = s * (1.0f / EMB);
    float vs = 0.f;
#pragma unroll
    for (int j = 0; j < 8; ++j) { x[j] -= mean; vs += x[j] * x[j]; }
#pragma unroll
    for (int off = 32; off; off >>= 1) vs += __shfl_xor(vs, off);
    float rstd = rsqrtf(vs * (1.0f / EMB) + 1e-5f);
    float4 g0 = *reinterpret_cast<const float4*>(&g[l * 8]);
    float4 g1 = *reinterpret_cast<const float4*>(&g[l * 8 + 4]);
    float4 c0 = *reinterpret_cast<const float4*>(&bb[l * 8]);
    float4 c1 = *reinterpret_cast<const float4*>(&bb[l * 8 + 4]);
    short8 o;
    o[0] = (short)f2bfu(x[0] * rstd * g0.x + c0.x);
    o[1] = (short)f2bfu(x[1] * rstd * g0.y + c0.y);
    o[2] = (short)f2bfu(x[2] * rstd * g0.z + c0.z);
    o[3] = (short)f2bfu(x[3] * rstd * g0.w + c0.w);
    o[4] = (short)f2bfu(x[4] * rstd * g1.x + c1.x);
    o[5] = (short)f2bfu(x[5] * rstd * g1.y + c1.y);
    o[6] = (short)f2bfu(x[6] * rstd * g1.z + c1.z);
    o[7] = (short)f2bfu(x[7] * rstd * g1.w + c1.w);
    *reinterpret_cast<short8*>(&hb[base]) = o;
}

// ---- batched weight transpose+convert, ALL layers: f32 [K][N] -> bf16 [N][K]
__global__ __launch_bounds__(256) void transp_v12(
    const float* __restrict__ qW, const float* __restrict__ kW,
    const float* __restrict__ vW, const float* __restrict__ pW,
    const float* __restrict__ m1W, const float* __restrict__ m2W,
    short* __restrict__ WtAll)
{
    __shared__ short tile[64][68];
    int bid0 = blockIdx.x, t = threadIdx.x;
    int layer = bid0 / 768;
    int bid = bid0 - layer * 768;
    const long we = (long)layer * EMB * EMB;
    const long wm1 = (long)layer * EMB * 2048;
    short* Wt = WtAll + (long)layer * WT_L;
    const float* W; short* Dt; int K, N, nkt, tl;
    if (bid < 192)      { int w = bid / 64; tl = bid % 64;
                          W = ((w == 0) ? qW : (w == 1) ? kW : vW) + we;
                          Dt = Wt + w * 262144; K = 512; N = 512; nkt = 8; }
    else if (bid < 256) { tl = bid - 192; W = pW + we;  Dt = Wt + 786432;  K = 512;  N = 512;  nkt = 8; }
    else if (bid < 512) { tl = bid - 256; W = m1W + wm1; Dt = Wt + 1048576; K = 512;  N = 2048; nkt = 8; }
    else                { tl = bid - 512; W = m2W + wm1; Dt = Wt + 2097152; K = 2048; N = 512;  nkt = 32; }
    int k0 = (tl % nkt) * 64, n0 = (tl / nkt) * 64;
    int c = t & 63, r4 = t >> 6;
#pragma unroll
    for (int p = 0; p < 16; ++p) {
        int r = r4 + p * 4;
        tile[r][c] = (short)f2bfu(W[(long)(k0 + r) * N + n0 + c]);
    }
    __syncthreads();
#pragma unroll
    for (int p = 0; p < 16; ++p) {
        int rr = r4 + p * 4;
        Dt[(long)(n0 + rr) * K + k0 + c] = tile[c][rr];
    }
}

// ------- MFMA GEMM v18: dbuf K-loop, counted vmcnt; BM template -------------
// bsplit=1: V-cols (>=1024) write transposed to VT[bh][d][s] instead of C.
template <int BM>
__global__ __launch_bounds__(256) void gemm_v18(
    const bf16* __restrict__ A, const short* __restrict__ Wt,
    const float* __restrict__ b0, const float* __restrict__ b1,
    const float* __restrict__ b2, bf16* __restrict__ C,
    bf16* __restrict__ VT,
    int N, int K, int nbx, int act, int bsplit)
{
    constexpr int NF = (BM == 128) ? 4 : 2;     // n-frags per wave
    constexpr int AC = BM / 32;                 // A chunks per wave per stage
    __shared__ short As[2][BM * 64];
    __shared__ short Bs[2][128 * 64];
    int t = threadIdx.x;
    int nb = gridDim.x;
    int bid = blockIdx.x;
    bid = (bid & 7) * (nb >> 3) + (bid >> 3);   // XCD swizzle (bijective)
    int row0 = (bid / nbx) * BM;
    int col0 = (bid % nbx) * 128;
    int wid = t >> 6, l = t & 63;
    int wm = (BM == 128) ? (wid >> 1) : 0;
    int wn = (BM == 128) ? (wid & 1) : wid;
    int l15 = l & 15, l4 = l >> 4;
    int lrow = l >> 3, lslot = l & 7;
    int kn = K >> 6;

    f32x4 acc[4][NF] = {};

    auto stage = [&](int buf, int k0) {
#pragma unroll
        for (int c = 0; c < AC; ++c) {
            int chunk = wid * AC + c;
            int row = chunk * 8 + lrow;
            int gs = lslot ^ (row & 7);
            gload_lds16(&A[(long)(row0 + row) * K + k0 + gs * 8], &As[buf][chunk * 512]);
        }
#pragma unroll
        for (int c = 0; c < 4; ++c) {
            int chunk = wid * 4 + c;
            int row = chunk * 8 + lrow;
            int gs = lslot ^ (row & 7);
            gload_lds16(&Wt[(long)(col0 + row) * K + k0 + gs * 8], &Bs[buf][chunk * 512]);
        }
    };

    stage(0, 0);
    for (int kt = 0; kt < kn; ++kt) {
        int cur = kt & 1;
        if (kt + 1 < kn) {
            stage(cur ^ 1, (kt + 1) * 64);
            if constexpr (BM == 128)
                asm volatile("s_waitcnt vmcnt(8)" ::: "memory");
            else
                asm volatile("s_waitcnt vmcnt(6)" ::: "memory");
        } else {
            asm volatile("s_waitcnt vmcnt(0)" ::: "memory");
        }
        __builtin_amdgcn_s_barrier();
        __builtin_amdgcn_sched_barrier(0);
#pragma unroll
        for (int ks = 0; ks < 2; ++ks) {
            short8 af[4], bfr[NF];
#pragma unroll
            for (int m = 0; m < 4; ++m) {
                int r = wm * 64 + m * 16 + l15;
                af[m] = *reinterpret_cast<const short8*>(&As[cur][r * 64 + (((ks * 4 + l4) ^ (r & 7)) * 8)]);
            }
#pragma unroll
            for (int n = 0; n < NF; ++n) {
                int r = wn * (NF * 16) + n * 16 + l15;
                bfr[n] = *reinterpret_cast<const short8*>(&Bs[cur][r * 64 + (((ks * 4 + l4) ^ (r & 7)) * 8)]);
            }
#pragma unroll
            for (int m = 0; m < 4; ++m)
#pragma unroll
                for (int n = 0; n < NF; ++n)
                    acc[m][n] = __builtin_amdgcn_mfma_f32_16x16x32_bf16(bfr[n], af[m], acc[m][n], 0, 0, 0);
        }
        asm volatile("s_waitcnt lgkmcnt(0)" ::: "memory");
        __builtin_amdgcn_s_barrier();
    }
    // epilogue: lane holds C[row][col = ... + l4*4 + 0..3]
    bool vblock = (bsplit && col0 >= 1024);
#pragma unroll
    for (int m = 0; m < 4; ++m) {
        int row = row0 + wm * 64 + m * 16 + l15;
#pragma unroll
        for (int n = 0; n < NF; ++n) {
            int col = col0 + wn * (NF * 16) + n * 16 + l4 * 4;
            const float* bp = bsplit ? (col < 512 ? &b0[col] : col < 1024 ? &b1[col - 512] : &b2[col - 1024])
                                     : &b0[col];
            float4 bv = *reinterpret_cast<const float4*>(bp);
            float qs = (bsplit && col < 512) ? QSCALE : 1.0f;
            float v0 = (acc[m][n][0] + bv.x) * qs;
            float v1 = (acc[m][n][1] + bv.y) * qs;
            float v2 = (acc[m][n][2] + bv.z) * qs;
            float v3 = (acc[m][n][3] + bv.w) * qs;
            if (act) {
                v0 = fast_gelu(v0);
                v1 = fast_gelu(v1);
                v2 = fast_gelu(v2);
                v3 = fast_gelu(v3);
            }
            if (vblock) {
                int b = row / S3;
                int s = row - b * S3;
                int hhd = col - 1024;            // hh*64 + d
                long vbase = ((long)(b * 8 + (hhd >> 6)) * 64 + (hhd & 63)) * S3 + s;
                VT[vbase]          = f2bf(v0);
                VT[vbase + S3]     = f2bf(v1);
                VT[vbase + 2 * S3] = f2bf(v2);
                VT[vbase + 3 * S3] = f2bf(v3);
            } else {
                ushort4 o;
                o.x = f2bfu(v0); o.y = f2bfu(v1); o.z = f2bfu(v2); o.w = f2bfu(v3);
                *reinterpret_cast<ushort4*>(&C[(long)row * N + col]) = o;
            }
        }
    }
}

// ------- MFMA flash attention v17 -------------------------------------------
__global__ __launch_bounds__(256) void flash_v17(
    const bf16* __restrict__ QKV, const bf16* __restrict__ VT,
    bf16* __restrict__ O)
{
    __shared__ short QPs[4096], Ks[2][4096], Vs[2][4096];   // 40,960 B
    int t = threadIdx.x;
    int bid = blockIdx.x;
    int qb = 23 - (bid >> 6);        // heavy blocks launch first
    int bh = bid & 63;
    int b = bh >> 3, hh = bh & 7;
    long baseq = (long)b * S3 * QKV_STR + hh * 64;
    long basev = (long)bh * 64 * S3;          // VT[bh][d][s]
    long baseo = (long)b * S3 * EMB + hh * 64;
    int q0 = qb * 64;
    int wid = t >> 6, l = t & 63;
    int l15 = l & 15, l4 = l >> 4;
    int lrow = l >> 3, lslot = l & 7;

#pragma unroll
    for (int c = 0; c < 2; ++c) {
        int chunk = c * 4 + wid;
        int row = chunk * 8 + lrow;
        int gs = lslot ^ (row & 7);
        gload_lds16(&QKV[baseq + (long)(q0 + row) * QKV_STR + gs * 8], &QPs[chunk * 512]);
    }
#pragma unroll
    for (int c = 0; c < 2; ++c) {
        int chunk = c * 4 + wid;
        int row = chunk * 8 + lrow;
        int gs = lslot ^ (row & 7);
        gload_lds16(&QKV[baseq + 512 + (long)row * QKV_STR + gs * 8], &Ks[0][chunk * 512]);
        gload_lds16(&VT[basev + (long)row * S3 + gs * 8], &Vs[0][chunk * 512]);
    }
    asm volatile("s_waitcnt vmcnt(4)" ::: "memory");   // Q's 2 loads done
    __builtin_amdgcn_s_barrier();                      // Qs visible to all waves
    short8 qf[2];
    {
        int rq = wid * 16 + l15;
#pragma unroll
        for (int ks = 0; ks < 2; ++ks)
            qf[ks] = *reinterpret_cast<const short8*>(&QPs[rq * 64 + (((ks * 4 + l4) ^ (rq & 7)) * 8)]);
    }
    asm volatile("s_waitcnt lgkmcnt(0)" ::: "memory"); // hoist reads complete

    f32x4 oacc[4] = {};
    float li = 0.f;

    for (int kt = 0; kt <= qb; ++kt) {
        int cur = kt & 1;
        if (kt < qb) {
            int k1 = (kt + 1) * 64;
#pragma unroll
            for (int c = 0; c < 2; ++c) {
                int chunk = c * 4 + wid;
                int row = chunk * 8 + lrow;
                int gs = lslot ^ (row & 7);
                gload_lds16(&QKV[baseq + 512 + (long)(k1 + row) * QKV_STR + gs * 8], &Ks[cur ^ 1][chunk * 512]);
                gload_lds16(&VT[basev + (long)row * S3 + k1 + gs * 8], &Vs[cur ^ 1][chunk * 512]);
            }
            asm volatile("s_waitcnt vmcnt(4)" ::: "memory");
        } else {
            asm volatile("s_waitcnt vmcnt(0)" ::: "memory");
        }
        __builtin_amdgcn_s_barrier();
        __builtin_amdgcn_sched_barrier(0);

        f32x4 s[4] = {};
#pragma unroll
        for (int ks = 0; ks < 2; ++ks) {
#pragma unroll
            for (int n = 0; n < 4; ++n) {
                int rk = n * 16 + l15;
                short8 kf = *reinterpret_cast<const short8*>(&Ks[cur][rk * 64 + (((ks * 4 + l4) ^ (rk & 7)) * 8)]);
                s[n] = __builtin_amdgcn_mfma_f32_16x16x32_bf16(kf, qf[ks], s[n], 0, 0, 0);
            }
        }
        if (kt == qb) {
            int qloc = wid * 16 + l15;
#pragma unroll
            for (int n = 0; n < 4; ++n) {
#pragma unroll
                for (int r = 0; r < 4; ++r)
                    if (n * 16 + l4 * 4 + r > qloc) s[n][r] = -1e30f;
            }
        }
        float rs = 0.f;
#pragma unroll
        for (int n = 0; n < 4; ++n)
#pragma unroll
            for (int r = 0; r < 4; ++r) {
                float p = exp2f(s[n][r]);
                s[n][r] = p;
                rs += p;
            }
        rs += __shfl_xor(rs, 16);
        rs += __shfl_xor(rs, 32);
        li += rs;
        {
            int qrow = wid * 16 + l15;
#pragma unroll
            for (int n = 0; n < 4; ++n) {
                ushort4 pk;
                pk.x = f2bfu(s[n][0]); pk.y = f2bfu(s[n][1]);
                pk.z = f2bfu(s[n][2]); pk.w = f2bfu(s[n][3]);
                int slot = n * 2 + (l4 >> 1);
                *reinterpret_cast<ushort4*>(
                    &QPs[qrow * 64 + ((slot ^ (qrow & 7)) * 8) + (l4 & 1) * 4]) = pk;
            }
        }
#pragma unroll
        for (int ks = 0; ks < 2; ++ks) {
            int prow = wid * 16 + l15;
            short8 pa = *reinterpret_cast<const short8*>(
                &QPs[prow * 64 + (((ks * 4 + l4) ^ (prow & 7)) * 8)]);
#pragma unroll
            for (int n = 0; n < 4; ++n) {
                int rk = n * 16 + l15;
                short8 vb = *reinterpret_cast<const short8*>(&Vs[cur][rk * 64 + (((ks * 4 + l4) ^ (rk & 7)) * 8)]);
                oacc[n] = __builtin_amdgcn_mfma_f32_16x16x32_bf16(pa, vb, oacc[n], 0, 0, 0);
            }
        }
        asm volatile("s_waitcnt lgkmcnt(0)" ::: "memory");
        __builtin_amdgcn_s_barrier();
    }
    float lir[4];
#pragma unroll
    for (int r = 0; r < 4; ++r)
        lir[r] = __shfl(li, (l & 48) | (l4 * 4 + r));
    int rowb = q0 + wid * 16 + l4 * 4;
#pragma unroll
    for (int n = 0; n < 4; ++n) {
        int col = n * 16 + l15;
#pragma unroll
        for (int r = 0; r < 4; ++r)
            O[baseo + (long)(rowb + r) * EMB + col] = f2bf(oacc[n][r] / lir[r]);
    }
}

// ------- heads v13: 8 tokens/block, 8-lane dot groups, weights in regs ------
__global__ __launch_bounds__(256) void heads_v13(
    const bf16* __restrict__ hb,
    const float* __restrict__ hdR_W, const float* __restrict__ hdR_b,
    const float* __restrict__ hdS_W, const float* __restrict__ hdS_b,
    const float* __restrict__ hdA_W, const float* __restrict__ hdA_b,
    float* __restrict__ out)
{
    __shared__ short rows[16][512];
    int tid = threadIdx.x;
    int tok0 = blockIdx.x * 8;
#pragma unroll
    for (int p = 0; p < 4; ++p) {
        int i = p * 256 + tid;
        int rowIdx = i >> 6;
        int seg = i & 63;
        int tk = rowIdx >> 1, which = rowIdx & 1;
        int tokg = tok0 + tk;
        int b = tokg >> 9, tt = tokg & 511;
        long gaddr = ((long)b * S3 + 3L * tt + 1 + which) * EMB + seg * 8;
        *reinterpret_cast<short8*>(&rows[rowIdx][seg * 8]) =
            *reinterpret_cast<const short8*>(&hb[gaddr]);
    }
    __syncthreads();
    int o = tid >> 3, g = tid & 7;
    if (o >= 24) return;
    int which = (o >= 17 && o < 23) ? 0 : 1;
    float wreg[64];
#pragma unroll
    for (int i2 = 0; i2 < 64; ++i2) {
        int kk = g * 64 + i2;
        wreg[i2] = (o < 17) ? hdS_W[kk * 17 + o]
                 : (o < 23) ? hdA_W[kk * 6 + (o - 17)]
                            : hdR_W[kk];
    }
#pragma unroll
    for (int tk = 0; tk < 8; ++tk) {
        const short* src = &rows[tk * 2 + which][g * 64];
        float sum = 0.f;
#pragma unroll
        for (int i2 = 0; i2 < 8; ++i2) {
            short8 v = *reinterpret_cast<const short8*>(&src[i2 * 8]);
#pragma unroll
            for (int j = 0; j < 8; ++j)
                sum = fmaf(bfu2f((unsigned short)v[j]), wreg[i2 * 8 + j], sum);
        }
        sum += __shfl_xor(sum, 1);
        sum += __shfl_xor(sum, 2);
        sum += __shfl_xor(sum, 4);
        if (g == 0) {
            int tokg = tok0 + tk;
            if (o < 17)       out[(long)tokg * 17 + o] = sum + hdS_b[o];
            else if (o < 23)  out[69632 + (long)tokg * 6 + (o - 17)] = tanhf(sum + hdA_b[o - 17]);
            else              out[94208 + tokg] = sum + hdR_b[0];
        }
    }
}

extern "C" void kernel_launch(void* const* d_in, const int* in_sizes, int n_in,
                              void* d_out, int out_size, void* d_ws, size_t ws_size,
                              hipStream_t stream) {
    const float* state   = (const float*)d_in[0];
    const float* action  = (const float*)d_in[1];
    const float* reward  = (const float*)d_in[2];
    const int*   timestep= (const int*)  d_in[3];
    const float* sW   = (const float*)d_in[4];
    const float* sb   = (const float*)d_in[5];
    const float* aW   = (const float*)d_in[6];
    const float* ab   = (const float*)d_in[7];
    const float* rW   = (const float*)d_in[8];
    const float* rb   = (const float*)d_in[9];
    const float* temb = (const float*)d_in[10];
    const float* lnE_g= (const float*)d_in[11];
    const float* lnE_b= (const float*)d_in[12];
    const float* qW   = (const float*)d_in[13];
    const float* qb_  = (const float*)d_in[14];
    const float* kW   = (const float*)d_in[15];
    const float* kb_  = (const float*)d_in[16];
    const float* vW   = (const float*)d_in[17];
    const float* vb_  = (const float*)d_in[18];
    const float* pW   = (const float*)d_in[19];
    const float* pb_  = (const float*)d_in[20];
    const float* ln1_g= (const float*)d_in[21];
    const float* ln1_b= (const float*)d_in[22];
    const float* m1W  = (const float*)d_in[23];
    const float* m1b  = (const float*)d_in[24];
    const float* m2W  = (const float*)d_in[25];
    const float* m2b  = (const float*)d_in[26];
    const float* ln2_g= (const float*)d_in[27];
    const float* ln2_b= (const float*)d_in[28];
    const float* hdR_W= (const float*)d_in[29];
    const float* hdR_b= (const float*)d_in[30];
    const float* hdS_W= (const float*)d_in[31];
    const float* hdS_b= (const float*)d_in[32];
    const float* hdA_W= (const float*)d_in[33];
    const float* hdA_b= (const float*)d_in[34];

    // ws layout (bytes), total 94,371,840 (verified available):
    // hb bf16 @0 | qkv @12582912 | att @50331648 | xb/vT @62914560 |
    // Wt(3 layers) @75497472 (18,874,368). m [NROWS][2048] aliases qkv+att.
    if (ws_size < 94371840u) return;
    char* wsb = (char*)d_ws;
    bf16* hb   = (bf16*)wsb;
    bf16* qkv  = (bf16*)(wsb + 12582912);
    bf16* att  = (bf16*)(wsb + 50331648);
    bf16* xb   = (bf16*)(wsb + 62914560);
    bf16* vT   = xb;
    bf16* m    = qkv;
    short* Wt  = (short*)(wsb + 75497472);

    embed_v9<<<NTOK, 256, 0, stream>>>(state, action, reward, timestep,
                                       sW, sb, aW, ab, rW, rb, temb, hb);
    addln_v13<<<NROWS / 4, 256, 0, stream>>>(hb, nullptr, lnE_g, lnE_b, 0);
    transp_v12<<<3 * 768, 256, 0, stream>>>(qW, kW, vW, pW, m1W, m2W, Wt);

    for (int i = 0; i < 3; ++i) {
        short* Wl = Wt + (long)i * WT_L;
        gemm_v18<64><<<192 * 12, 256, 0, stream>>>(hb, Wl, qb_ + i * EMB, kb_ + i * EMB,
                                                   vb_ + i * EMB, qkv, vT, 1536, 512, 12, 0, 1);
        flash_v17<<<24 * 64, 256, 0, stream>>>(qkv, vT, att);
        gemm_v18<64><<<192 * 4, 256, 0, stream>>>(att, Wl + 786432, pb_ + i * EMB,
                                                  nullptr, nullptr, xb, nullptr, 512, 512, 4, 0, 0);
        addln_v13<<<NROWS / 4, 256, 0, stream>>>(hb, xb, ln1_g + i * EMB, ln1_b + i * EMB, 1);
        gemm_v18<128><<<96 * 16, 256, 0, stream>>>(hb, Wl + 1048576, m1b + i * 2048,
                                                   nullptr, nullptr, m, nullptr, 2048, 512, 16, 1, 0);
        gemm_v18<64><<<192 * 4, 256, 0, stream>>>(m, Wl + 2097152, m2b + i * EMB,
                                                  nullptr, nullptr, xb, nullptr, 512, 2048, 4, 0, 0);
        addln_v13<<<NROWS / 4, 256, 0, stream>>>(hb, xb, ln2_g + i * EMB, ln2_b + i * EMB, 1);
    }

    heads_v13<<<NTOK / 8, 256, 0, stream>>>(hb, hdR_W, hdR_b, hdS_W, hdS_b,
                                            hdA_W, hdA_b, (float*)d_out);
}

// Round 19
// 634.187 us; speedup vs baseline: 1.0284x; 1.0284x over previous
//
#include <hip/hip_runtime.h>
#include <hip/hip_bf16.h>

// Decision Transformer forward, round 19.
// - gemm templated <BM, DB>: m1 = BM=128 single-buffer (best measured:
//   <=50us vs 56 BM=64/dbuf vs 58.6 BM=128/dbuf — dbuf at BM=128 halves
//   occupancy); qkv/proj/m2 = BM=64 dbuf (r17 win).
// B=8 T=512 S3=1536 E=512 H=8 D=64 L=3 FF=2048 MS=4096

#define S3 1536
#define EMB 512
#define NROWS 12288   // B*S3
#define NTOK 4096     // B*T
#define QKV_STR 1536
#define QSCALE 0.18033688f  // 0.125 * log2(e)
#define WT_L 3145728        // Wt elements per layer

typedef __hip_bfloat16 bf16;
typedef __attribute__((ext_vector_type(8))) short short8;   // 8 bf16
typedef __attribute__((ext_vector_type(4))) float f32x4;

__device__ inline float bf2f(bf16 b) { return __bfloat162float(b); }
__device__ inline bf16 f2bf(float f) { return __float2bfloat16(f); }
__device__ inline unsigned short f2bfu(float f) {
    bf16 h = __float2bfloat16(f);
    return *reinterpret_cast<unsigned short*>(&h);
}
__device__ inline float bfu2f(unsigned short v) {
    bf16 h = *reinterpret_cast<bf16*>(&v);
    return __bfloat162float(h);
}
__device__ inline float fast_gelu(float v) {
    float u = v * fmaf(v * v, 0.0356774081f, 0.7978845608f);
    return v * __builtin_amdgcn_rcpf(1.0f + exp2f(u * -2.885390082f));
}

__device__ inline void gload_lds16(const void* g, void* lds) {
    __builtin_amdgcn_global_load_lds(
        (const __attribute__((address_space(1))) void*)g,
        (__attribute__((address_space(3))) void*)lds, 16, 0, 0);
}

// ---------------- embed: writes bf16 residual stream ----------------
__global__ __launch_bounds__(256) void embed_v9(
    const float* __restrict__ state, const float* __restrict__ action,
    const float* __restrict__ reward, const int* __restrict__ timestep,
    const float* __restrict__ sW, const float* __restrict__ sb,
    const float* __restrict__ aW, const float* __restrict__ ab,
    const float* __restrict__ rW, const float* __restrict__ rb,
    const float* __restrict__ temb, bf16* __restrict__ hb)
{
    int tok = blockIdx.x;
    int b = tok >> 9;
    int t = tok & 511;
    int tid = threadIdx.x;
    int ts = timestep[tok];
    long hbase = ((long)b * S3 + 3L * t) * EMB;
    const float* st = state + (long)tok * 17;
    const float* ac = action + (long)tok * 6;
    float rw = reward[tok];
    float sv[17], av[6];
#pragma unroll
    for (int j = 0; j < 17; ++j) sv[j] = st[j];
#pragma unroll
    for (int j = 0; j < 6; ++j) av[j] = ac[j];
    for (int c = tid; c < EMB; c += 256) {
        float te = temb[(long)ts * EMB + c];
        float re = rw * rW[c] + rb[c] + te;
        float se = sb[c] + te;
#pragma unroll
        for (int j = 0; j < 17; ++j) se = fmaf(sv[j], sW[j * EMB + c], se);
        float ae = ab[c] + te;
#pragma unroll
        for (int j = 0; j < 6; ++j) ae = fmaf(av[j], aW[j * EMB + c], ae);
        hb[hbase + c] = f2bf(re);
        hb[hbase + EMB + c] = f2bf(se);
        hb[hbase + 2 * EMB + c] = f2bf(ae);
    }
}

// ------- (add+)layernorm, wave-per-row, shfl-only ---------
__global__ __launch_bounds__(256) void addln_v13(
    bf16* __restrict__ hb, const bf16* __restrict__ delta,
    const float* __restrict__ g, const float* __restrict__ bb, int hasDelta)
{
    int tid = threadIdx.x;
    int w = tid >> 6, l = tid & 63;
    long row = (long)blockIdx.x * 4 + w;
    long base = row * EMB + l * 8;
    short8 xv = *reinterpret_cast<const short8*>(&hb[base]);
    float x[8];
#pragma unroll
    for (int j = 0; j < 8; ++j) x[j] = bfu2f((unsigned short)xv[j]);
    if (hasDelta) {
        short8 dv = *reinterpret_cast<const short8*>(&delta[base]);
#pragma unroll
        for (int j = 0; j < 8; ++j) x[j] += bfu2f((unsigned short)dv[j]);
    }
    float s = 0.f;
#pragma unroll
    for (int j = 0; j < 8; ++j) s += x[j];
#pragma unroll
    for (int off = 32; off; off >>= 1) s += __shfl_xor(s, off);
    float mean = s * (1.0f / EMB);
    float vs = 0.f;
#pragma unroll
    for (int j = 0; j < 8; ++j) { x[j] -= mean; vs += x[j] * x[j]; }
#pragma unroll
    for (int off = 32; off; off >>= 1) vs += __shfl_xor(vs, off);
    float rstd = rsqrtf(vs * (1.0f / EMB) + 1e-5f);
    float4 g0 = *reinterpret_cast<const float4*>(&g[l * 8]);
    float4 g1 = *reinterpret_cast<const float4*>(&g[l * 8 + 4]);
    float4 c0 = *reinterpret_cast<const float4*>(&bb[l * 8]);
    float4 c1 = *reinterpret_cast<const float4*>(&bb[l * 8 + 4]);
    short8 o;
    o[0] = (short)f2bfu(x[0] * rstd * g0.x + c0.x);
    o[1] = (short)f2bfu(x[1] * rstd * g0.y + c0.y);
    o[2] = (short)f2bfu(x[2] * rstd * g0.z + c0.z);
    o[3] = (short)f2bfu(x[3] * rstd * g0.w + c0.w);
    o[4] = (short)f2bfu(x[4] * rstd * g1.x + c1.x);
    o[5] = (short)f2bfu(x[5] * rstd * g1.y + c1.y);
    o[6] = (short)f2bfu(x[6] * rstd * g1.z + c1.z);
    o[7] = (short)f2bfu(x[7] * rstd * g1.w + c1.w);
    *reinterpret_cast<short8*>(&hb[base]) = o;
}

// ---- batched weight transpose+convert, ALL layers: f32 [K][N] -> bf16 [N][K]
__global__ __launch_bounds__(256) void transp_v12(
    const float* __restrict__ qW, const float* __restrict__ kW,
    const float* __restrict__ vW, const float* __restrict__ pW,
    const float* __restrict__ m1W, const float* __restrict__ m2W,
    short* __restrict__ WtAll)
{
    __shared__ short tile[64][68];
    int bid0 = blockIdx.x, t = threadIdx.x;
    int layer = bid0 / 768;
    int bid = bid0 - layer * 768;
    const long we = (long)layer * EMB * EMB;
    const long wm1 = (long)layer * EMB * 2048;
    short* Wt = WtAll + (long)layer * WT_L;
    const float* W; short* Dt; int K, N, nkt, tl;
    if (bid < 192)      { int w = bid / 64; tl = bid % 64;
                          W = ((w == 0) ? qW : (w == 1) ? kW : vW) + we;
                          Dt = Wt + w * 262144; K = 512; N = 512; nkt = 8; }
    else if (bid < 256) { tl = bid - 192; W = pW + we;  Dt = Wt + 786432;  K = 512;  N = 512;  nkt = 8; }
    else if (bid < 512) { tl = bid - 256; W = m1W + wm1; Dt = Wt + 1048576; K = 512;  N = 2048; nkt = 8; }
    else                { tl = bid - 512; W = m2W + wm1; Dt = Wt + 2097152; K = 2048; N = 512;  nkt = 32; }
    int k0 = (tl % nkt) * 64, n0 = (tl / nkt) * 64;
    int c = t & 63, r4 = t >> 6;
#pragma unroll
    for (int p = 0; p < 16; ++p) {
        int r = r4 + p * 4;
        tile[r][c] = (short)f2bfu(W[(long)(k0 + r) * N + n0 + c]);
    }
    __syncthreads();
#pragma unroll
    for (int p = 0; p < 16; ++p) {
        int rr = r4 + p * 4;
        Dt[(long)(n0 + rr) * K + k0 + c] = tile[c][rr];
    }
}

// ------- MFMA GEMM v19: template <BM, DB> ----------------------------------
// DB=1: double-buffered K-loop + counted vmcnt. DB=0: single buffer,
// __syncthreads loop (best for BM=128: 32KB LDS keeps >=3 blocks/CU).
// bsplit=1: V-cols (>=1024) write transposed to VT[bh][d][s].
template <int BM, int DB>
__global__ __launch_bounds__(256) void gemm_v19(
    const bf16* __restrict__ A, const short* __restrict__ Wt,
    const float* __restrict__ b0, const float* __restrict__ b1,
    const float* __restrict__ b2, bf16* __restrict__ C,
    bf16* __restrict__ VT,
    int N, int K, int nbx, int act, int bsplit)
{
    constexpr int NF = (BM == 128) ? 4 : 2;     // n-frags per wave
    constexpr int AC = BM / 32;                 // A chunks per wave per stage
    constexpr int NBUF = DB ? 2 : 1;
    __shared__ short As[NBUF][BM * 64];
    __shared__ short Bs[NBUF][128 * 64];
    int t = threadIdx.x;
    int nb = gridDim.x;
    int bid = blockIdx.x;
    bid = (bid & 7) * (nb >> 3) + (bid >> 3);   // XCD swizzle (bijective)
    int row0 = (bid / nbx) * BM;
    int col0 = (bid % nbx) * 128;
    int wid = t >> 6, l = t & 63;
    int wm = (BM == 128) ? (wid >> 1) : 0;
    int wn = (BM == 128) ? (wid & 1) : wid;
    int l15 = l & 15, l4 = l >> 4;
    int lrow = l >> 3, lslot = l & 7;
    int kn = K >> 6;

    f32x4 acc[4][NF] = {};

    auto stage = [&](int buf, int k0) {
#pragma unroll
        for (int c = 0; c < AC; ++c) {
            int chunk = wid * AC + c;
            int row = chunk * 8 + lrow;
            int gs = lslot ^ (row & 7);
            gload_lds16(&A[(long)(row0 + row) * K + k0 + gs * 8], &As[buf][chunk * 512]);
        }
#pragma unroll
        for (int c = 0; c < 4; ++c) {
            int chunk = wid * 4 + c;
            int row = chunk * 8 + lrow;
            int gs = lslot ^ (row & 7);
            gload_lds16(&Wt[(long)(col0 + row) * K + k0 + gs * 8], &Bs[buf][chunk * 512]);
        }
    };
    auto compute = [&](int buf) {
#pragma unroll
        for (int ks = 0; ks < 2; ++ks) {
            short8 af[4], bfr[NF];
#pragma unroll
            for (int m = 0; m < 4; ++m) {
                int r = wm * 64 + m * 16 + l15;
                af[m] = *reinterpret_cast<const short8*>(&As[buf][r * 64 + (((ks * 4 + l4) ^ (r & 7)) * 8)]);
            }
#pragma unroll
            for (int n = 0; n < NF; ++n) {
                int r = wn * (NF * 16) + n * 16 + l15;
                bfr[n] = *reinterpret_cast<const short8*>(&Bs[buf][r * 64 + (((ks * 4 + l4) ^ (r & 7)) * 8)]);
            }
#pragma unroll
            for (int m = 0; m < 4; ++m)
#pragma unroll
                for (int n = 0; n < NF; ++n)
                    acc[m][n] = __builtin_amdgcn_mfma_f32_16x16x32_bf16(bfr[n], af[m], acc[m][n], 0, 0, 0);
        }
    };

    if constexpr (DB) {
        stage(0, 0);
        for (int kt = 0; kt < kn; ++kt) {
            int cur = kt & 1;
            if (kt + 1 < kn) {
                stage(cur ^ 1, (kt + 1) * 64);
                if constexpr (BM == 128)
                    asm volatile("s_waitcnt vmcnt(8)" ::: "memory");
                else
                    asm volatile("s_waitcnt vmcnt(6)" ::: "memory");
            } else {
                asm volatile("s_waitcnt vmcnt(0)" ::: "memory");
            }
            __builtin_amdgcn_s_barrier();
            __builtin_amdgcn_sched_barrier(0);
            compute(cur);
            asm volatile("s_waitcnt lgkmcnt(0)" ::: "memory");
            __builtin_amdgcn_s_barrier();
        }
    } else {
        for (int kt = 0; kt < kn; ++kt) {
            stage(0, kt * 64);
            __syncthreads();
            compute(0);
            __syncthreads();
        }
    }
    // epilogue: lane holds C[row][col = ... + l4*4 + 0..3]
    bool vblock = (bsplit && col0 >= 1024);
#pragma unroll
    for (int m = 0; m < 4; ++m) {
        int row = row0 + wm * 64 + m * 16 + l15;
#pragma unroll
        for (int n = 0; n < NF; ++n) {
            int col = col0 + wn * (NF * 16) + n * 16 + l4 * 4;
            const float* bp = bsplit ? (col < 512 ? &b0[col] : col < 1024 ? &b1[col - 512] : &b2[col - 1024])
                                     : &b0[col];
            float4 bv = *reinterpret_cast<const float4*>(bp);
            float qs = (bsplit && col < 512) ? QSCALE : 1.0f;
            float v0 = (acc[m][n][0] + bv.x) * qs;
            float v1 = (acc[m][n][1] + bv.y) * qs;
            float v2 = (acc[m][n][2] + bv.z) * qs;
            float v3 = (acc[m][n][3] + bv.w) * qs;
            if (act) {
                v0 = fast_gelu(v0);
                v1 = fast_gelu(v1);
                v2 = fast_gelu(v2);
                v3 = fast_gelu(v3);
            }
            if (vblock) {
                int b = row / S3;
                int s = row - b * S3;
                int hhd = col - 1024;            // hh*64 + d
                long vbase = ((long)(b * 8 + (hhd >> 6)) * 64 + (hhd & 63)) * S3 + s;
                VT[vbase]          = f2bf(v0);
                VT[vbase + S3]     = f2bf(v1);
                VT[vbase + 2 * S3] = f2bf(v2);
                VT[vbase + 3 * S3] = f2bf(v3);
            } else {
                ushort4 o;
                o.x = f2bfu(v0); o.y = f2bfu(v1); o.z = f2bfu(v2); o.w = f2bfu(v3);
                *reinterpret_cast<ushort4*>(&C[(long)row * N + col]) = o;
            }
        }
    }
}

// ------- MFMA flash attention v17 -------------------------------------------
__global__ __launch_bounds__(256) void flash_v17(
    const bf16* __restrict__ QKV, const bf16* __restrict__ VT,
    bf16* __restrict__ O)
{
    __shared__ short QPs[4096], Ks[2][4096], Vs[2][4096];   // 40,960 B
    int t = threadIdx.x;
    int bid = blockIdx.x;
    int qb = 23 - (bid >> 6);        // heavy blocks launch first
    int bh = bid & 63;
    int b = bh >> 3, hh = bh & 7;
    long baseq = (long)b * S3 * QKV_STR + hh * 64;
    long basev = (long)bh * 64 * S3;          // VT[bh][d][s]
    long baseo = (long)b * S3 * EMB + hh * 64;
    int q0 = qb * 64;
    int wid = t >> 6, l = t & 63;
    int l15 = l & 15, l4 = l >> 4;
    int lrow = l >> 3, lslot = l & 7;

#pragma unroll
    for (int c = 0; c < 2; ++c) {
        int chunk = c * 4 + wid;
        int row = chunk * 8 + lrow;
        int gs = lslot ^ (row & 7);
        gload_lds16(&QKV[baseq + (long)(q0 + row) * QKV_STR + gs * 8], &QPs[chunk * 512]);
    }
#pragma unroll
    for (int c = 0; c < 2; ++c) {
        int chunk = c * 4 + wid;
        int row = chunk * 8 + lrow;
        int gs = lslot ^ (row & 7);
        gload_lds16(&QKV[baseq + 512 + (long)row * QKV_STR + gs * 8], &Ks[0][chunk * 512]);
        gload_lds16(&VT[basev + (long)row * S3 + gs * 8], &Vs[0][chunk * 512]);
    }
    asm volatile("s_waitcnt vmcnt(4)" ::: "memory");   // Q's 2 loads done
    __builtin_amdgcn_s_barrier();                      // Qs visible to all waves
    short8 qf[2];
    {
        int rq = wid * 16 + l15;
#pragma unroll
        for (int ks = 0; ks < 2; ++ks)
            qf[ks] = *reinterpret_cast<const short8*>(&QPs[rq * 64 + (((ks * 4 + l4) ^ (rq & 7)) * 8)]);
    }
    asm volatile("s_waitcnt lgkmcnt(0)" ::: "memory"); // hoist reads complete

    f32x4 oacc[4] = {};
    float li = 0.f;

    for (int kt = 0; kt <= qb; ++kt) {
        int cur = kt & 1;
        if (kt < qb) {
            int k1 = (kt + 1) * 64;
#pragma unroll
            for (int c = 0; c < 2; ++c) {
                int chunk = c * 4 + wid;
                int row = chunk * 8 + lrow;
                int gs = lslot ^ (row & 7);
                gload_lds16(&QKV[baseq + 512 + (long)(k1 + row) * QKV_STR + gs * 8], &Ks[cur ^ 1][chunk * 512]);
                gload_lds16(&VT[basev + (long)row * S3 + k1 + gs * 8], &Vs[cur ^ 1][chunk * 512]);
            }
            asm volatile("s_waitcnt vmcnt(4)" ::: "memory");
        } else {
            asm volatile("s_waitcnt vmcnt(0)" ::: "memory");
        }
        __builtin_amdgcn_s_barrier();
        __builtin_amdgcn_sched_barrier(0);

        f32x4 s[4] = {};
#pragma unroll
        for (int ks = 0; ks < 2; ++ks) {
#pragma unroll
            for (int n = 0; n < 4; ++n) {
                int rk = n * 16 + l15;
                short8 kf = *reinterpret_cast<const short8*>(&Ks[cur][rk * 64 + (((ks * 4 + l4) ^ (rk & 7)) * 8)]);
                s[n] = __builtin_amdgcn_mfma_f32_16x16x32_bf16(kf, qf[ks], s[n], 0, 0, 0);
            }
        }
        if (kt == qb) {
            int qloc = wid * 16 + l15;
#pragma unroll
            for (int n = 0; n < 4; ++n) {
#pragma unroll
                for (int r = 0; r < 4; ++r)
                    if (n * 16 + l4 * 4 + r > qloc) s[n][r] = -1e30f;
            }
        }
        float rs = 0.f;
#pragma unroll
        for (int n = 0; n < 4; ++n)
#pragma unroll
            for (int r = 0; r < 4; ++r) {
                float p = exp2f(s[n][r]);
                s[n][r] = p;
                rs += p;
            }
        rs += __shfl_xor(rs, 16);
        rs += __shfl_xor(rs, 32);
        li += rs;
        {
            int qrow = wid * 16 + l15;
#pragma unroll
            for (int n = 0; n < 4; ++n) {
                ushort4 pk;
                pk.x = f2bfu(s[n][0]); pk.y = f2bfu(s[n][1]);
                pk.z = f2bfu(s[n][2]); pk.w = f2bfu(s[n][3]);
                int slot = n * 2 + (l4 >> 1);
                *reinterpret_cast<ushort4*>(
                    &QPs[qrow * 64 + ((slot ^ (qrow & 7)) * 8) + (l4 & 1) * 4]) = pk;
            }
        }
#pragma unroll
        for (int ks = 0; ks < 2; ++ks) {
            int prow = wid * 16 + l15;
            short8 pa = *reinterpret_cast<const short8*>(
                &QPs[prow * 64 + (((ks * 4 + l4) ^ (prow & 7)) * 8)]);
#pragma unroll
            for (int n = 0; n < 4; ++n) {
                int rk = n * 16 + l15;
                short8 vb = *reinterpret_cast<const short8*>(&Vs[cur][rk * 64 + (((ks * 4 + l4) ^ (rk & 7)) * 8)]);
                oacc[n] = __builtin_amdgcn_mfma_f32_16x16x32_bf16(pa, vb, oacc[n], 0, 0, 0);
            }
        }
        asm volatile("s_waitcnt lgkmcnt(0)" ::: "memory");
        __builtin_amdgcn_s_barrier();
    }
    float lir[4];
#pragma unroll
    for (int r = 0; r < 4; ++r)
        lir[r] = __shfl(li, (l & 48) | (l4 * 4 + r));
    int rowb = q0 + wid * 16 + l4 * 4;
#pragma unroll
    for (int n = 0; n < 4; ++n) {
        int col = n * 16 + l15;
#pragma unroll
        for (int r = 0; r < 4; ++r)
            O[baseo + (long)(rowb + r) * EMB + col] = f2bf(oacc[n][r] / lir[r]);
    }
}

// ------- heads v13: 8 tokens/block, 8-lane dot groups, weights in regs ------
__global__ __launch_bounds__(256) void heads_v13(
    const bf16* __restrict__ hb,
    const float* __restrict__ hdR_W, const float* __restrict__ hdR_b,
    const float* __restrict__ hdS_W, const float* __restrict__ hdS_b,
    const float* __restrict__ hdA_W, const float* __restrict__ hdA_b,
    float* __restrict__ out)
{
    __shared__ short rows[16][512];
    int tid = threadIdx.x;
    int tok0 = blockIdx.x * 8;
#pragma unroll
    for (int p = 0; p < 4; ++p) {
        int i = p * 256 + tid;
        int rowIdx = i >> 6;
        int seg = i & 63;
        int tk = rowIdx >> 1, which = rowIdx & 1;
        int tokg = tok0 + tk;
        int b = tokg >> 9, tt = tokg & 511;
        long gaddr = ((long)b * S3 + 3L * tt + 1 + which) * EMB + seg * 8;
        *reinterpret_cast<short8*>(&rows[rowIdx][seg * 8]) =
            *reinterpret_cast<const short8*>(&hb[gaddr]);
    }
    __syncthreads();
    int o = tid >> 3, g = tid & 7;
    if (o >= 24) return;
    int which = (o >= 17 && o < 23) ? 0 : 1;
    float wreg[64];
#pragma unroll
    for (int i2 = 0; i2 < 64; ++i2) {
        int kk = g * 64 + i2;
        wreg[i2] = (o < 17) ? hdS_W[kk * 17 + o]
                 : (o < 23) ? hdA_W[kk * 6 + (o - 17)]
                            : hdR_W[kk];
    }
#pragma unroll
    for (int tk = 0; tk < 8; ++tk) {
        const short* src = &rows[tk * 2 + which][g * 64];
        float sum = 0.f;
#pragma unroll
        for (int i2 = 0; i2 < 8; ++i2) {
            short8 v = *reinterpret_cast<const short8*>(&src[i2 * 8]);
#pragma unroll
            for (int j = 0; j < 8; ++j)
                sum = fmaf(bfu2f((unsigned short)v[j]), wreg[i2 * 8 + j], sum);
        }
        sum += __shfl_xor(sum, 1);
        sum += __shfl_xor(sum, 2);
        sum += __shfl_xor(sum, 4);
        if (g == 0) {
            int tokg = tok0 + tk;
            if (o < 17)       out[(long)tokg * 17 + o] = sum + hdS_b[o];
            else if (o < 23)  out[69632 + (long)tokg * 6 + (o - 17)] = tanhf(sum + hdA_b[o - 17]);
            else              out[94208 + tokg] = sum + hdR_b[0];
        }
    }
}

extern "C" void kernel_launch(void* const* d_in, const int* in_sizes, int n_in,
                              void* d_out, int out_size, void* d_ws, size_t ws_size,
                              hipStream_t stream) {
    const float* state   = (const float*)d_in[0];
    const float* action  = (const float*)d_in[1];
    const float* reward  = (const float*)d_in[2];
    const int*   timestep= (const int*)  d_in[3];
    const float* sW   = (const float*)d_in[4];
    const float* sb   = (const float*)d_in[5];
    const float* aW   = (const float*)d_in[6];
    const float* ab   = (const float*)d_in[7];
    const float* rW   = (const float*)d_in[8];
    const float* rb   = (const float*)d_in[9];
    const float* temb = (const float*)d_in[10];
    const float* lnE_g= (const float*)d_in[11];
    const float* lnE_b= (const float*)d_in[12];
    const float* qW   = (const float*)d_in[13];
    const float* qb_  = (const float*)d_in[14];
    const float* kW   = (const float*)d_in[15];
    const float* kb_  = (const float*)d_in[16];
    const float* vW   = (const float*)d_in[17];
    const float* vb_  = (const float*)d_in[18];
    const float* pW   = (const float*)d_in[19];
    const float* pb_  = (const float*)d_in[20];
    const float* ln1_g= (const float*)d_in[21];
    const float* ln1_b= (const float*)d_in[22];
    const float* m1W  = (const float*)d_in[23];
    const float* m1b  = (const float*)d_in[24];
    const float* m2W  = (const float*)d_in[25];
    const float* m2b  = (const float*)d_in[26];
    const float* ln2_g= (const float*)d_in[27];
    const float* ln2_b= (const float*)d_in[28];
    const float* hdR_W= (const float*)d_in[29];
    const float* hdR_b= (const float*)d_in[30];
    const float* hdS_W= (const float*)d_in[31];
    const float* hdS_b= (const float*)d_in[32];
    const float* hdA_W= (const float*)d_in[33];
    const float* hdA_b= (const float*)d_in[34];

    // ws layout (bytes), total 94,371,840 (verified available):
    // hb bf16 @0 | qkv @12582912 | att @50331648 | xb/vT @62914560 |
    // Wt(3 layers) @75497472 (18,874,368). m [NROWS][2048] aliases qkv+att.
    if (ws_size < 94371840u) return;
    char* wsb = (char*)d_ws;
    bf16* hb   = (bf16*)wsb;
    bf16* qkv  = (bf16*)(wsb + 12582912);
    bf16* att  = (bf16*)(wsb + 50331648);
    bf16* xb   = (bf16*)(wsb + 62914560);
    bf16* vT   = xb;
    bf16* m    = qkv;
    short* Wt  = (short*)(wsb + 75497472);

    embed_v9<<<NTOK, 256, 0, stream>>>(state, action, reward, timestep,
                                       sW, sb, aW, ab, rW, rb, temb, hb);
    addln_v13<<<NROWS / 4, 256, 0, stream>>>(hb, nullptr, lnE_g, lnE_b, 0);
    transp_v12<<<3 * 768, 256, 0, stream>>>(qW, kW, vW, pW, m1W, m2W, Wt);

    for (int i = 0; i < 3; ++i) {
        short* Wl = Wt + (long)i * WT_L;
        gemm_v19<64, 1><<<192 * 12, 256, 0, stream>>>(hb, Wl, qb_ + i * EMB, kb_ + i * EMB,
                                                      vb_ + i * EMB, qkv, vT, 1536, 512, 12, 0, 1);
        flash_v17<<<24 * 64, 256, 0, stream>>>(qkv, vT, att);
        gemm_v19<64, 1><<<192 * 4, 256, 0, stream>>>(att, Wl + 786432, pb_ + i * EMB,
                                                     nullptr, nullptr, xb, nullptr, 512, 512, 4, 0, 0);
        addln_v13<<<NROWS / 4, 256, 0, stream>>>(hb, xb, ln1_g + i * EMB, ln1_b + i * EMB, 1);
        gemm_v19<128, 0><<<96 * 16, 256, 0, stream>>>(hb, Wl + 1048576, m1b + i * 2048,
                                                      nullptr, nullptr, m, nullptr, 2048, 512, 16, 1, 0);
        gemm_v19<64, 1><<<192 * 4, 256, 0, stream>>>(m, Wl + 2097152, m2b + i * EMB,
                                                     nullptr, nullptr, xb, nullptr, 512, 2048, 4, 0, 0);
        addln_v13<<<NROWS / 4, 256, 0, stream>>>(hb, xb, ln2_g + i * EMB, ln2_b + i * EMB, 1);
    }

    heads_v13<<<NTOK / 8, 256, 0, stream>>>(hb, hdR_W, hdR_b, hdS_W, hdS_b,
                                            hdA_W, hdA_b, (float*)d_out);
}